// Round 17
// baseline (17.157 us; speedup 1.0000x reference)
//
#include <hip/hip_runtime.h>

#define NN 1024
#define DD 64
#define NF 11
#define TI 8
#define BT 1024

// Softmax-without-max is exact here: valid scores are in (-1, 0], masked keys
// contribute exactly +0.0, len >= 1 so every row-sum > 0.
//
// R17 = R16 (2 gens + wave-dead skip + row-owning epilogue) with DEAD-WAVE
// STORES HOISTED BEFORE THE BARRIER: ~47% of output bytes (the masked zero
// columns) issue during live-wave compute instead of in the tail, halving the
// final generation's exposed store drain. Dead waves also skip the partials
// zero-write when their 256-column chunk is never read by the reducer
// ((tid & ~255) >= len, wave-uniform). Output bit-identical to R16.
__global__ __launch_bounds__(BT, 8) void featuresim_kernel(
    const float* __restrict__ x,
    const int* __restrict__ x_lengths,
    const float* __restrict__ fimp,
    float* __restrict__ out)
{
    const int tid = threadIdx.x;
    const int b   = blockIdx.x >> 7;            // 128 row-groups per batch
    const int i0  = (blockIdx.x & 127) * TI;
    const int len = x_lengths[b];

    // wave-uniform: this wave's 64 keys are all masked -> all outputs 0
    const bool wave_dead = (tid & ~63) >= len;

    __shared__ float partials[TI][BT];    // 32 KiB -> 2 blocks/CU co-resident

    if (wave_dead) {
        // issue the zero output stores NOW — they depend on nothing and
        // drain under the live waves' compute phase.
        #pragma unroll
        for (int r = 0; r < TI; ++r)
            out[(size_t)(b * NN + i0 + r) * NN + tid] = 0.0f;
        // partials zeros only needed if the reducer reads this chunk
        if ((tid & ~255) < len) {
            #pragma unroll
            for (int r = 0; r < TI; ++r)
                partials[r][tid] = 0.0f;
        }
    } else {
        // feature_importance: uniform -> SGPRs
        float fi[NF];
        #pragma unroll
        for (int k = 0; k < NF; ++k) fi[k] = fimp[k];

        // this thread's key row j = tid
        float fj[NF];
        {
            const float4* p = reinterpret_cast<const float4*>(
                x + (size_t)(b * NN + tid) * DD);
            float4 a = p[0], c = p[1], d = p[2];
            fj[0] = a.x; fj[1] = a.y; fj[2]  = a.z; fj[3] = a.w;
            fj[4] = c.x; fj[5] = c.y; fj[6]  = c.z; fj[7] = c.w;
            fj[8] = d.x; fj[9] = d.y; fj[10] = d.z;
        }
        const bool valid = tid < len;   // partial wave masks per-lane

        #pragma unroll
        for (int r = 0; r < TI; ++r) {
            const float* qp = x + (size_t)(b * NN + i0 + r) * DD;  // uniform -> s_load
            float s = 0.0f;
            #pragma unroll
            for (int k = 0; k < NF; ++k) {
                float d = qp[k] - fj[k];
                s = fmaf(-fabsf(d), fi[k], s);     // -abs() via VOP3 input mod
            }
            float val = (s > -1.0f) ? s : 0.0f;
            partials[r][tid] = valid ? __expf(val) : 0.0f;
        }
    }
    __syncthreads();                      // the ONLY barrier

    // ---- epilogue: wave w owns row w end-to-end; waves 8-15 retire now
    const int lane = tid & 63;
    const int wid  = tid >> 6;
    if (wid < TI) {
        float4 v[4];
        float s = 0.0f;
        #pragma unroll
        for (int m = 0; m < 4; ++m) {
            if (256 * m < len) {          // wave-uniform; skipped chunks are all 0
                v[m] = *reinterpret_cast<const float4*>(
                    &partials[wid][lane * 4 + 256 * m]);
            } else {
                v[m] = make_float4(0.0f, 0.0f, 0.0f, 0.0f);
            }
            s += (v[m].x + v[m].y) + (v[m].z + v[m].w);
        }
        #pragma unroll
        for (int off = 32; off >= 1; off >>= 1)
            s += __shfl_xor(s, off, 64);

        const float inv = __builtin_amdgcn_rcpf(s);
        float4* rowp = reinterpret_cast<float4*>(
            out + (size_t)(b * NN + i0 + wid) * NN);
        #pragma unroll
        for (int m = 0; m < 4; ++m) {
            float4 o = make_float4(v[m].x * inv, v[m].y * inv,
                                   v[m].z * inv, v[m].w * inv);
            rowp[lane + 64 * m] = o;      // 1KB per wave-instr, coalesced
        }
    }
    // kernel ends with stores in flight -> drain overlaps the next generation
}

extern "C" void kernel_launch(void* const* d_in, const int* in_sizes, int n_in,
                              void* d_out, int out_size, void* d_ws, size_t ws_size,
                              hipStream_t stream) {
    const float* x    = (const float*)d_in[0];
    const int*   xlen = (const int*)d_in[1];
    const float* fimp = (const float*)d_in[2];
    float*       out  = (float*)d_out;

    const int B = in_sizes[1];                  // 8
    dim3 grid(B * (NN / TI));                   // 1024 blocks = 2 generations
    dim3 block(BT);
    featuresim_kernel<<<grid, block, 0, stream>>>(x, xlen, fimp, out);
}

// Round 18
// 16.885 us; speedup vs baseline: 1.0161x; 1.0161x over previous
//
#include <hip/hip_runtime.h>

#define NN 1024
#define DD 64
#define NF 11
#define TI 8
#define BT 1024

// Softmax-without-max is exact here: valid scores are in (-1, 0], masked keys
// contribute exactly +0.0, len >= 1 so every row-sum > 0.
//
// R18 = R16 WITHOUT the redundant dead-wave output stores: the row-owning
// epilogue already writes the FULL 1024-wide row (zeros included), so the
// dead-wave column stores duplicated ~47% of output bytes since R13 (~16MB
// of extra store instrs + L2 write traffic; TCC line-merge hid it from HBM
// WRITE_SIZE). Dead waves also skip partials zero-writes for 256-col chunks
// the reducer never reads ((tid & ~255) >= len, wave-uniform). Bytes written
// are bit-identical to R16.
__global__ __launch_bounds__(BT, 8) void featuresim_kernel(
    const float* __restrict__ x,
    const int* __restrict__ x_lengths,
    const float* __restrict__ fimp,
    float* __restrict__ out)
{
    const int tid = threadIdx.x;
    const int b   = blockIdx.x >> 7;            // 128 row-groups per batch
    const int i0  = (blockIdx.x & 127) * TI;
    const int len = x_lengths[b];

    // wave-uniform: this wave's 64 keys are all masked -> all outputs 0
    const bool wave_dead = (tid & ~63) >= len;

    __shared__ float partials[TI][BT];    // 32 KiB -> 2 blocks/CU co-resident

    if (wave_dead) {
        // zero partials ONLY for chunks the reducer will read; no out stores
        // (the epilogue writes the full row, including every masked column).
        if ((tid & ~255) < len) {
            #pragma unroll
            for (int r = 0; r < TI; ++r)
                partials[r][tid] = 0.0f;
        }
    } else {
        // feature_importance: uniform -> SGPRs
        float fi[NF];
        #pragma unroll
        for (int k = 0; k < NF; ++k) fi[k] = fimp[k];

        // this thread's key row j = tid
        float fj[NF];
        {
            const float4* p = reinterpret_cast<const float4*>(
                x + (size_t)(b * NN + tid) * DD);
            float4 a = p[0], c = p[1], d = p[2];
            fj[0] = a.x; fj[1] = a.y; fj[2]  = a.z; fj[3] = a.w;
            fj[4] = c.x; fj[5] = c.y; fj[6]  = c.z; fj[7] = c.w;
            fj[8] = d.x; fj[9] = d.y; fj[10] = d.z;
        }
        const bool valid = tid < len;   // partial wave masks per-lane

        #pragma unroll
        for (int r = 0; r < TI; ++r) {
            const float* qp = x + (size_t)(b * NN + i0 + r) * DD;  // uniform -> s_load
            float s = 0.0f;
            #pragma unroll
            for (int k = 0; k < NF; ++k) {
                float d = qp[k] - fj[k];
                s = fmaf(-fabsf(d), fi[k], s);     // -abs() via VOP3 input mod
            }
            float val = (s > -1.0f) ? s : 0.0f;
            partials[r][tid] = valid ? __expf(val) : 0.0f;
        }
    }
    __syncthreads();                      // the ONLY barrier (no stores before it)

    // ---- epilogue: wave w owns row w end-to-end (full row incl. zeros);
    // waves 8-15 retire at the barrier.
    const int lane = tid & 63;
    const int wid  = tid >> 6;
    if (wid < TI) {
        float4 v[4];
        float s = 0.0f;
        #pragma unroll
        for (int m = 0; m < 4; ++m) {
            if (256 * m < len) {          // wave-uniform; skipped chunks are all 0
                v[m] = *reinterpret_cast<const float4*>(
                    &partials[wid][lane * 4 + 256 * m]);
            } else {
                v[m] = make_float4(0.0f, 0.0f, 0.0f, 0.0f);
            }
            s += (v[m].x + v[m].y) + (v[m].z + v[m].w);
        }
        #pragma unroll
        for (int off = 32; off >= 1; off >>= 1)
            s += __shfl_xor(s, off, 64);

        const float inv = __builtin_amdgcn_rcpf(s);
        float4* rowp = reinterpret_cast<float4*>(
            out + (size_t)(b * NN + i0 + wid) * NN);
        #pragma unroll
        for (int m = 0; m < 4; ++m) {
            float4 o = make_float4(v[m].x * inv, v[m].y * inv,
                                   v[m].z * inv, v[m].w * inv);
            rowp[lane + 64 * m] = o;      // 1KB per wave-instr, coalesced
        }
    }
    // kernel ends with stores in flight -> drain overlaps the next generation
}

extern "C" void kernel_launch(void* const* d_in, const int* in_sizes, int n_in,
                              void* d_out, int out_size, void* d_ws, size_t ws_size,
                              hipStream_t stream) {
    const float* x    = (const float*)d_in[0];
    const int*   xlen = (const int*)d_in[1];
    const float* fimp = (const float*)d_in[2];
    float*       out  = (float*)d_out;

    const int B = in_sizes[1];                  // 8
    dim3 grid(B * (NN / TI));                   // 1024 blocks = 2 generations
    dim3 block(BT);
    featuresim_kernel<<<grid, block, 0, stream>>>(x, xlen, fimp, out);
}

// Round 20
// 15.398 us; speedup vs baseline: 1.1142x; 1.0966x over previous
//
#include <hip/hip_runtime.h>

#define NN 1024
#define DD 64
#define NF 11
#define TI 8
#define BT 1024

typedef float vfloat4 __attribute__((ext_vector_type(4)));  // clang vector:
// __builtin_nontemporal_store requires a native vector type, not HIP's
// struct-based float4.

// Softmax-without-max is exact here: valid scores are in (-1, 0], masked keys
// contribute exactly +0.0, len >= 1 so every row-sum > 0.
//
// R20 = R18 + NONTEMPORAL epilogue stores (R19 re-spun past the compile
// error): the 33.5MB output is write-once-never-read and equals the entire
// aggregate L2 (32MB). Default write-allocate streams every output line
// through L2 (allocate + evict + writeback) and thrashes the x-slab lines
// gen-2 needs. nontemporal_store emits the MUBUF `nt` variant, bypassing L2
// allocation. Bytes written are bit-identical to R18.
__global__ __launch_bounds__(BT, 8) void featuresim_kernel(
    const float* __restrict__ x,
    const int* __restrict__ x_lengths,
    const float* __restrict__ fimp,
    float* __restrict__ out)
{
    const int tid = threadIdx.x;
    const int b   = blockIdx.x >> 7;            // 128 row-groups per batch
    const int i0  = (blockIdx.x & 127) * TI;
    const int len = x_lengths[b];

    // wave-uniform: this wave's 64 keys are all masked -> all outputs 0
    const bool wave_dead = (tid & ~63) >= len;

    __shared__ float partials[TI][BT];    // 32 KiB -> 2 blocks/CU co-resident

    if (wave_dead) {
        // zero partials ONLY for chunks the reducer will read; no out stores
        // (the epilogue writes the full row, including every masked column).
        if ((tid & ~255) < len) {
            #pragma unroll
            for (int r = 0; r < TI; ++r)
                partials[r][tid] = 0.0f;
        }
    } else {
        // feature_importance: uniform -> SGPRs
        float fi[NF];
        #pragma unroll
        for (int k = 0; k < NF; ++k) fi[k] = fimp[k];

        // this thread's key row j = tid
        float fj[NF];
        {
            const float4* p = reinterpret_cast<const float4*>(
                x + (size_t)(b * NN + tid) * DD);
            float4 a = p[0], c = p[1], d = p[2];
            fj[0] = a.x; fj[1] = a.y; fj[2]  = a.z; fj[3] = a.w;
            fj[4] = c.x; fj[5] = c.y; fj[6]  = c.z; fj[7] = c.w;
            fj[8] = d.x; fj[9] = d.y; fj[10] = d.z;
        }
        const bool valid = tid < len;   // partial wave masks per-lane

        #pragma unroll
        for (int r = 0; r < TI; ++r) {
            const float* qp = x + (size_t)(b * NN + i0 + r) * DD;  // uniform -> s_load
            float s = 0.0f;
            #pragma unroll
            for (int k = 0; k < NF; ++k) {
                float d = qp[k] - fj[k];
                s = fmaf(-fabsf(d), fi[k], s);     // -abs() via VOP3 input mod
            }
            float val = (s > -1.0f) ? s : 0.0f;
            partials[r][tid] = valid ? __expf(val) : 0.0f;
        }
    }
    __syncthreads();                      // the ONLY barrier (no stores before it)

    // ---- epilogue: wave w owns row w end-to-end (full row incl. zeros);
    // waves 8-15 retire at the barrier.
    const int lane = tid & 63;
    const int wid  = tid >> 6;
    if (wid < TI) {
        float4 v[4];
        float s = 0.0f;
        #pragma unroll
        for (int m = 0; m < 4; ++m) {
            if (256 * m < len) {          // wave-uniform; skipped chunks are all 0
                v[m] = *reinterpret_cast<const float4*>(
                    &partials[wid][lane * 4 + 256 * m]);
            } else {
                v[m] = make_float4(0.0f, 0.0f, 0.0f, 0.0f);
            }
            s += (v[m].x + v[m].y) + (v[m].z + v[m].w);
        }
        #pragma unroll
        for (int off = 32; off >= 1; off >>= 1)
            s += __shfl_xor(s, off, 64);

        const float inv = __builtin_amdgcn_rcpf(s);
        vfloat4* rowp = reinterpret_cast<vfloat4*>(
            out + (size_t)(b * NN + i0 + wid) * NN);
        #pragma unroll
        for (int m = 0; m < 4; ++m) {
            vfloat4 o = { v[m].x * inv, v[m].y * inv,
                          v[m].z * inv, v[m].w * inv };
            __builtin_nontemporal_store(o, &rowp[lane + 64 * m]);  // nt, 1KB/instr
        }
    }
    // kernel ends with stores in flight -> drain overlaps the next generation
}

extern "C" void kernel_launch(void* const* d_in, const int* in_sizes, int n_in,
                              void* d_out, int out_size, void* d_ws, size_t ws_size,
                              hipStream_t stream) {
    const float* x    = (const float*)d_in[0];
    const int*   xlen = (const int*)d_in[1];
    const float* fimp = (const float*)d_in[2];
    float*       out  = (float*)d_out;

    const int B = in_sizes[1];                  // 8
    dim3 grid(B * (NN / TI));                   // 1024 blocks = 2 generations
    dim3 block(BT);
    featuresim_kernel<<<grid, block, 0, stream>>>(x, xlen, fimp, out);
}